// Round 1
// baseline (280.428 us; speedup 1.0000x reference)
//
#include <hip/hip_runtime.h>
#include <math.h>

#define TPB 256
#define NBLOCKS 2048

// ws layout: [0] double ce_sum, [1] u64 c01 (TN | FP<<32), [2] u64 c23 (FN | TP<<32)

__global__ __launch_bounds__(TPB) void detloss_main(
    const float4* __restrict__ out4,   // outputs viewed as float4 (2 elements each)
    const int4*   __restrict__ lab4,   // labels viewed as int4 (4 elements each)
    double* __restrict__ ce_sum,
    unsigned long long* __restrict__ c01,
    unsigned long long* __restrict__ c23,
    int nchunks)                       // B / 4
{
    float ce = 0.0f;
    unsigned long long cnt = 0ull;     // 4 x 16-bit packed counters: idx = label*2 + pred

    const int stride = gridDim.x * blockDim.x;
    for (int g = blockIdx.x * blockDim.x + threadIdx.x; g < nchunks; g += stride) {
        const int4   lb = lab4[g];
        const float4 a  = out4[2 * g];
        const float4 b  = out4[2 * g + 1];

        {
            const float o0 = a.x, o1 = a.y; const int l = lb.x;
            const float m = fmaxf(o0, o1);
            ce += m + log1pf(__expf(-fabsf(o0 - o1))) - (l ? o1 : o0);
            const int pred = (o1 > o0) ? 1 : 0;
            cnt += 1ull << ((((l << 1) | pred)) << 4);
        }
        {
            const float o0 = a.z, o1 = a.w; const int l = lb.y;
            const float m = fmaxf(o0, o1);
            ce += m + log1pf(__expf(-fabsf(o0 - o1))) - (l ? o1 : o0);
            const int pred = (o1 > o0) ? 1 : 0;
            cnt += 1ull << ((((l << 1) | pred)) << 4);
        }
        {
            const float o0 = b.x, o1 = b.y; const int l = lb.z;
            const float m = fmaxf(o0, o1);
            ce += m + log1pf(__expf(-fabsf(o0 - o1))) - (l ? o1 : o0);
            const int pred = (o1 > o0) ? 1 : 0;
            cnt += 1ull << ((((l << 1) | pred)) << 4);
        }
        {
            const float o0 = b.z, o1 = b.w; const int l = lb.w;
            const float m = fmaxf(o0, o1);
            ce += m + log1pf(__expf(-fabsf(o0 - o1))) - (l ? o1 : o0);
            const int pred = (o1 > o0) ? 1 : 0;
            cnt += 1ull << ((((l << 1) | pred)) << 4);
        }
    }

    // wave (64-lane) shuffle reduction
    #pragma unroll
    for (int off = 32; off > 0; off >>= 1) {
        ce  += __shfl_down(ce, off);
        cnt += __shfl_down(cnt, off);
    }

    __shared__ float              s_ce[TPB / 64];
    __shared__ unsigned long long s_cnt[TPB / 64];
    const int wave = threadIdx.x >> 6;
    const int lane = threadIdx.x & 63;
    if (lane == 0) { s_ce[wave] = ce; s_cnt[wave] = cnt; }
    __syncthreads();

    if (threadIdx.x == 0) {
        float bce = 0.0f;
        unsigned long long bc = 0ull;
        #pragma unroll
        for (int w = 0; w < TPB / 64; ++w) { bce += s_ce[w]; bc += s_cnt[w]; }
        atomicAdd(ce_sum, (double)bce);
        const unsigned long long f0 =  bc        & 0xffffull;  // TN (label 0, pred 0)
        const unsigned long long f1 = (bc >> 16) & 0xffffull;  // FP (label 0, pred 1)
        const unsigned long long f2 = (bc >> 32) & 0xffffull;  // FN (label 1, pred 0)
        const unsigned long long f3 = (bc >> 48) & 0xffffull;  // TP (label 1, pred 1)
        atomicAdd(c01, f0 | (f1 << 32));
        atomicAdd(c23, f2 | (f3 << 32));
    }
}

__global__ void detloss_final(const double* __restrict__ ce_sum,
                              const unsigned long long* __restrict__ c01,
                              const unsigned long long* __restrict__ c23,
                              float* __restrict__ out, int B)
{
    const double invB = 1.0 / (double)B;
    const double ce = *ce_sum * invB;
    const unsigned long long a = *c01;
    const unsigned long long b = *c23;
    const double TN = (double)(a & 0xffffffffull);
    const double FP = (double)(a >> 32);
    const double FN = (double)(b & 0xffffffffull);
    const double TP = (double)(b >> 32);
    const bool nonzero = (TP > 0.0) && (TN > 0.0) && (FP > 0.0) && (FN > 0.0);
    const double ratio = (TP / fmax(TP + FN, 1.0)) * (FP / fmax(FP + TN, 1.0));
    const double coeff = nonzero ? (-0.5 * log(sqrt(fmax(ratio, 1e-30)))) : 0.5;
    // For N_CLASSES=2, M[pred,label]==1 only when pred=0 & label=1 => CS sum == FN
    const double meanCS = FN * invB;
    out[0] = (float)(ce + coeff * meanCS);
}

extern "C" void kernel_launch(void* const* d_in, const int* in_sizes, int n_in,
                              void* d_out, int out_size, void* d_ws, size_t ws_size,
                              hipStream_t stream) {
    const float* outputs = (const float*)d_in[0];
    const int*   labels  = (const int*)d_in[1];
    const int B = in_sizes[1];

    double*             ce_sum = (double*)d_ws;
    unsigned long long* c01    = (unsigned long long*)d_ws + 1;
    unsigned long long* c23    = (unsigned long long*)d_ws + 2;

    hipMemsetAsync(d_ws, 0, 32, stream);

    const int nchunks = B / 4;  // B = 2^24, divisible by 4
    detloss_main<<<NBLOCKS, TPB, 0, stream>>>(
        (const float4*)outputs, (const int4*)labels, ce_sum, c01, c23, nchunks);
    detloss_final<<<1, 1, 0, stream>>>(ce_sum, c01, c23, (float*)d_out, B);
}